// Round 1
// 3259.876 us; speedup vs baseline: 1.6239x; 1.6239x over previous
//
#include <hip/hip_runtime.h>
#include <cstdint>
#include <cstddef>

#define GLOBAL_AS __attribute__((address_space(1)))
#define LDS_AS    __attribute__((address_space(3)))

typedef _Float16 half4v __attribute__((ext_vector_type(4)));
typedef _Float16 half8v __attribute__((ext_vector_type(8)));
typedef float    f32x4  __attribute__((ext_vector_type(4)));

#define T_SEQ 128
#define NBATCH 32
#define HID   1024
#define VOCAB 32000
#define MROWS (T_SEQ * NBATCH)   // 4096
#define RNN_WGS 16               // weight-resident recurrence workgroups

// ---------------------------------------------------------------- utilities

__device__ __forceinline__ void load16_to_lds(const _Float16* gp, _Float16* lp) {
    // async global->LDS, 16B per lane; LDS dest must be wave-uniform base + lane*16
    __builtin_amdgcn_global_load_lds((const GLOBAL_AS uint32_t*)gp,
                                     (LDS_AS uint32_t*)lp, 16, 0, 0);
}

__device__ __forceinline__ float fast_tanh(float x) {
    // (e^2x - 1)/(e^2x + 1); clamp keeps e2 finite so inf*0 NaN can't happen
    float cx = fminf(fmaxf(x, -9.0f), 9.0f);
    float e2 = __expf(2.0f * cx);
    return (e2 - 1.0f) * __builtin_amdgcn_rcpf(e2 + 1.0f);
}

// ------------------------------------------------------------- conversions

// flat f32 -> f16, 4 elems/thread, grid-stride
__global__ __launch_bounds__(256) void cvt_f32_f16(const float4* __restrict__ src,
                                                   half4v* __restrict__ dst, int n4) {
    int i = blockIdx.x * 256 + threadIdx.x;
    int stride = gridDim.x * 256;
    for (; i < n4; i += stride) {
        float4 v = src[i];
        half4v h = {(_Float16)v.x, (_Float16)v.y, (_Float16)v.z, (_Float16)v.w};
        dst[i] = h;
    }
}

// x_h[r][:] = (f16) emb[ix[r]][:]   r = t*NBATCH+b
__global__ __launch_bounds__(256) void gather_x(const int* __restrict__ ix,
                                                const float4* __restrict__ emb4,
                                                half4v* __restrict__ x4) {
    int r = blockIdx.x;
    int t = threadIdx.x;
    int tok = ix[r];
    float4 v = emb4[(size_t)tok * 256 + t];
    half4v h = {(_Float16)v.x, (_Float16)v.y, (_Float16)v.z, (_Float16)v.w};
    x4[(size_t)r * 256 + t] = h;
}

// Build initial H fragment buffers (A-frag order) for both layers + zero flags.
// Frag layout: element (kt, mt, lane, e) = H[b = mt*16 + (lane&15)]
//                                          [k = kt*32 + (lane>>4)*8 + e]
// stored at half8v index (kt*2 + mt)*64 + lane.
__global__ __launch_bounds__(256) void hf_init(const float* __restrict__ hidden, // [2][32][1024]
                                               half8v* __restrict__ hf_l0,
                                               half8v* __restrict__ hf_l1,
                                               int* __restrict__ flags) {        // [256]
    int idx = blockIdx.x * 256 + threadIdx.x;   // 0..8191
    int l   = idx >> 12;
    int r   = idx & 4095;
    int kt   = r >> 7;
    int mt   = (r >> 6) & 1;
    int lane = r & 63;
    int b  = mt * 16 + (lane & 15);
    int k0 = kt * 32 + (lane >> 4) * 8;
    const float* s = hidden + ((size_t)l << 15) + ((size_t)b << 10) + k0;
    half8v h;
#pragma unroll
    for (int e = 0; e < 8; ++e) h[e] = (_Float16)s[e];
    (l ? hf_l1 : hf_l0)[r] = h;
    if (idx < 2 * T_SEQ) flags[idx] = 0;
}

// ------------------------------------------------------------- f16 MFMA GEMM
// C[M,N] = A[M,K] * B[N,K]^T + bias[N]    (m97 structure: 128x128 tile, BK=32,
// 256 thr = 4 waves each 64x64, global_load_lds 16B staging)
__global__ __launch_bounds__(256) void gemm_f16_bt(const _Float16* __restrict__ A,
                                                   const _Float16* __restrict__ B,
                                                   const float* __restrict__ bias,
                                                   float* __restrict__ C,
                                                   int M, int N, int K) {
    __shared__ __align__(16) _Float16 As[128 * 32];
    __shared__ __align__(16) _Float16 Bs[128 * 32];
    const int t    = threadIdx.x;
    const int lane = t & 63;
    const int wave = t >> 6;
    const int wm   = (wave >> 1) << 6;
    const int wn   = (wave & 1) << 6;
    const int lr   = lane & 15;
    const int quad = lane >> 4;
    const long mBase = (long)blockIdx.y << 7;
    const long nBase = (long)blockIdx.x << 7;

    const int srow = t >> 2;            // 4 threads/row, 16B each (32 f16 per row)
    const int scol = (t & 3) << 3;
    const _Float16* gA0 = A + (mBase + srow) * (long)K + scol;
    const _Float16* gA1 = A + (mBase + srow + 64) * (long)K + scol;
    const _Float16* gB0 = B + (nBase + srow) * (long)K + scol;
    const _Float16* gB1 = B + (nBase + srow + 64) * (long)K + scol;
    _Float16* lA0 = As + t * 8;
    _Float16* lA1 = As + (t + 256) * 8;
    _Float16* lB0 = Bs + t * 8;
    _Float16* lB1 = Bs + (t + 256) * 8;

    f32x4 acc[4][4] = {};

    for (int k0 = 0; k0 < K; k0 += 32) {
        load16_to_lds(gA0 + k0, lA0);
        load16_to_lds(gA1 + k0, lA1);
        load16_to_lds(gB0 + k0, lB0);
        load16_to_lds(gB1 + k0, lB1);
        __syncthreads();   // drains vmcnt before LDS reads

        half8v aF[4], bF[4];
#pragma unroll
        for (int i = 0; i < 4; ++i) {
            aF[i] = *(const half8v*)&As[(wm + i * 16 + lr) * 32 + quad * 8];
            bF[i] = *(const half8v*)&Bs[(wn + i * 16 + lr) * 32 + quad * 8];
        }
#pragma unroll
        for (int mi = 0; mi < 4; ++mi)
#pragma unroll
            for (int ni = 0; ni < 4; ++ni)
                acc[mi][ni] = __builtin_amdgcn_mfma_f32_16x16x32_f16(
                    aF[mi], bF[ni], acc[mi][ni], 0, 0, 0);
        __syncthreads();
    }

    // C/D layout: col = lane&15, row = quad*4 + r   (m89-verified)
#pragma unroll
    for (int ni = 0; ni < 4; ++ni) {
        long col = nBase + wn + ni * 16 + lr;
        float bv = bias ? bias[col] : 0.0f;
#pragma unroll
        for (int mi = 0; mi < 4; ++mi) {
            long row0 = mBase + wm + mi * 16 + quad * 4;
#pragma unroll
            for (int r = 0; r < 4; ++r)
                C[(row0 + r) * (long)N + col] = acc[mi][ni][r] + bv;
        }
    }
}

// ------------------------------------------------------------- RNN recurrence
// Weight-resident MFMA recurrence:
//   16 WGs, WG g owns output columns j in [64g, 64g+64).
//   Wh slice held ENTIRELY in registers as MFMA B-frags (128 VGPR/lane).
//   Per step: H_new[32,1024] = tanh(xw_t + H * Wh^T), H passed between WGs
//   through global ping-pong buffers stored in A-fragment order (coalesced
//   16B/lane reads, no LDS staging, no bank conflicts).
//   K (1024) split 4 ways across the WG's 4 waves -> LDS cross-wave reduce.
//   Step barrier: device-scope atomic counter + spin (16 WGs < 256 CUs =>
//   guaranteed co-resident; no cooperative launch needed).
__global__ __launch_bounds__(256, 1) void rnn_layer_mfma(
    const float* __restrict__ xw,        // [4096][1024]  x@Wi^T + b_ih (f32)
    const _Float16* __restrict__ wh,     // [1024][1024]  this layer's Wh (f16)
    const float* __restrict__ bh,        // [1024]
    const half8v* __restrict__ hf0,      // frag-ordered H buffer (even steps)
    half8v* __restrict__ hf1,            // frag-ordered H buffer (odd steps)
    _Float16* __restrict__ y,            // [4096][1024]  layer output (f16)
    float* __restrict__ hT,              // [32][1024]    final hidden (f32)
    int* __restrict__ flags)             // [128] zeroed step counters
{
    const int g    = blockIdx.x;         // j-slice
    const int tid  = threadIdx.x;
    const int w    = tid >> 6;           // wave: K-slice [256w, 256w+256)
    const int lane = tid & 63;
    const int lr   = lane & 15;
    const int quad = lane >> 4;
    const int jbase = g << 6;

    __shared__ float red[4][32][68];     // per-wave partials, padded (write: 2-way)

    // ---- preload B fragments (whole Wh slice resident in VGPRs) ----
    // bF[nt][kk] = Wh[jbase + nt*16 + lr][(8w+kk)*32 + quad*8 .. +8]
    half8v bF[4][8];
#pragma unroll
    for (int nt = 0; nt < 4; ++nt)
#pragma unroll
        for (int kk = 0; kk < 8; ++kk)
            bF[nt][kk] = *(const half8v*)&wh[(size_t)(jbase + nt * 16 + lr) * HID
                                             + ((8 * w + kk) * 32 + quad * 8)];

    // ---- reducer-role constants: this thread owns (b=rm, j=jbase+rn..+8) ----
    const int rm = tid >> 3;             // batch row 0..31
    const int rn = (tid & 7) << 3;       // local col 0..56
    float bhv[8];
#pragma unroll
    for (int e = 0; e < 8; ++e) bhv[e] = bh[jbase + rn + e];
    // frag-order H writeback slot for this thread's 8 values:
    //   kt = 2g + (rn>>5), mt = rm>>4, lane' = ((rn>>3)&3)*16 + (rm&15)
    const int houtIdx = ((2 * g + (rn >> 5)) * 2 + (rm >> 4)) * 64
                        + ((rn >> 3) & 3) * 16 + (rm & 15);

    const half8v* hbuf[2] = {hf0, (const half8v*)hf1};
    half8v* hbufw[2] = {(half8v*)hf0, hf1};

    for (int t = 0; t < T_SEQ; ++t) {
        const half8v* __restrict__ hin = hbuf[t & 1];
        half8v* __restrict__ hout      = hbufw[(t + 1) & 1];

        // xw prefetch (step-dependent only, independent of H)
        const float* xr = xw + ((size_t)(t * NBATCH + rm) << 10) + jbase + rn;
        float xv[8];
#pragma unroll
        for (int e = 0; e < 8; ++e) xv[e] = xr[e];

        // A fragments for this wave's K-slice (coalesced 16B/lane, L2/LLC-hit)
        half8v aF[2][8];
#pragma unroll
        for (int mt = 0; mt < 2; ++mt)
#pragma unroll
            for (int kk = 0; kk < 8; ++kk)
                aF[mt][kk] = hin[((8 * w + kk) * 2 + mt) * 64 + lane];

        f32x4 acc[2][4] = {};
#pragma unroll
        for (int kk = 0; kk < 8; ++kk)
#pragma unroll
            for (int mt = 0; mt < 2; ++mt)
#pragma unroll
                for (int nt = 0; nt < 4; ++nt)
                    acc[mt][nt] = __builtin_amdgcn_mfma_f32_16x16x32_f16(
                        aF[mt][kk], bF[nt][kk], acc[mt][nt], 0, 0, 0);

        // partials -> LDS   (C/D layout: col=lane&15, row=quad*4+r)
#pragma unroll
        for (int mt = 0; mt < 2; ++mt)
#pragma unroll
            for (int nt = 0; nt < 4; ++nt)
#pragma unroll
                for (int r = 0; r < 4; ++r)
                    red[w][mt * 16 + quad * 4 + r][nt * 16 + lr] = acc[mt][nt][r];
        __syncthreads();

        // cross-wave reduce + xw + bias + tanh; write y and frag-order H
        float v[8];
#pragma unroll
        for (int e = 0; e < 8; ++e) {
            float s = red[0][rm][rn + e] + red[1][rm][rn + e]
                    + red[2][rm][rn + e] + red[3][rm][rn + e];
            v[e] = fast_tanh(s + xv[e] + bhv[e]);
        }
        half8v hv;
#pragma unroll
        for (int e = 0; e < 8; ++e) hv[e] = (_Float16)v[e];
        *(half8v*)&y[((size_t)(t * NBATCH + rm) << 10) + jbase + rn] = hv;
        hout[houtIdx] = hv;
        if (t == T_SEQ - 1) {
#pragma unroll
            for (int e = 0; e < 8; ++e)
                hT[((size_t)rm << 10) + jbase + rn + e] = v[e];
        }

        // ---- step barrier across the 16 WGs ----
        __threadfence();                  // drain loads/stores, wb L2 (release)
        if (tid == 0) {
            __hip_atomic_fetch_add(&flags[t], 1, __ATOMIC_RELEASE,
                                   __HIP_MEMORY_SCOPE_AGENT);
            while (__hip_atomic_load(&flags[t], __ATOMIC_RELAXED,
                                     __HIP_MEMORY_SCOPE_AGENT) < RNN_WGS)
                __builtin_amdgcn_s_sleep(1);
        }
        __syncthreads();
        __threadfence();                  // acquire: invalidate L1/L2 before reads
    }
}

// ------------------------------------------------------------- log_softmax
// In-place per row of [4096][32000]; 3 passes (max / sumexp / subtract),
// passes 2-3 ride L2 (row = 128 KB just touched).
__global__ __launch_bounds__(256) void logsoftmax_rows(float* __restrict__ logits) {
    const long r = blockIdx.x;
    float4* row = (float4*)(logits + r * (long)VOCAB);   // 8000 float4
    __shared__ float red[256];
    const int t = threadIdx.x;

    float m = -3.4e38f;
    for (int i = t; i < 8000; i += 256) {
        float4 v = row[i];
        m = fmaxf(m, fmaxf(fmaxf(v.x, v.y), fmaxf(v.z, v.w)));
    }
    red[t] = m; __syncthreads();
    for (int o = 128; o > 0; o >>= 1) {
        if (t < o) red[t] = fmaxf(red[t], red[t + o]);
        __syncthreads();
    }
    m = red[0]; __syncthreads();

    float s = 0.0f;
    for (int i = t; i < 8000; i += 256) {
        float4 v = row[i];
        s += __expf(v.x - m) + __expf(v.y - m) + __expf(v.z - m) + __expf(v.w - m);
    }
    red[t] = s; __syncthreads();
    for (int o = 128; o > 0; o >>= 1) {
        if (t < o) red[t] += red[t + o];
        __syncthreads();
    }
    const float lse = m + __logf(red[0]);

    for (int i = t; i < 8000; i += 256) {
        float4 v = row[i];
        v.x -= lse; v.y -= lse; v.z -= lse; v.w -= lse;
        row[i] = v;
    }
}

// ------------------------------------------------------------------- launch

extern "C" void kernel_launch(void* const* d_in, const int* in_sizes, int n_in,
                              void* d_out, int out_size, void* d_ws, size_t ws_size,
                              hipStream_t stream) {
    const int*   ix    = (const int*)  d_in[0];
    const float* hid0  = (const float*)d_in[1];   // [2,32,1024]
    const float* emb   = (const float*)d_in[2];   // [32000,1024]
    const float* W_ih  = (const float*)d_in[3];   // [2,1024,1024]
    const float* W_hh  = (const float*)d_in[4];   // [2,1024,1024]
    const float* b_ih  = (const float*)d_in[5];   // [2,1024]
    const float* b_hh  = (const float*)d_in[6];   // [2,1024]
    const float* W_out = (const float*)d_in[7];   // [32000,1024]
    const float* b_out = (const float*)d_in[8];   // [32000]

    float* logits = (float*)d_out;                       // [4096][32000]
    float* hidT   = logits + (size_t)MROWS * VOCAB;      // [2][32][1024]

    char* ws = (char*)d_ws;
    _Float16* Wi_h   = (_Float16*)ws;  ws += (size_t)2 * 1024 * 1024 * sizeof(_Float16);
    _Float16* Wout_h = (_Float16*)ws;  ws += (size_t)VOCAB * 1024 * sizeof(_Float16);
    _Float16* Wh_h   = (_Float16*)ws;  ws += (size_t)2 * 1024 * 1024 * sizeof(_Float16);
    _Float16* x_h    = (_Float16*)ws;  ws += (size_t)MROWS * 1024 * sizeof(_Float16);
    _Float16* y_h    = (_Float16*)ws;  ws += (size_t)MROWS * 1024 * sizeof(_Float16);
    float*    xw     = (float*)ws;     ws += (size_t)MROWS * 1024 * sizeof(float);

    // H fragment ping-pong buffers + step flags live in the head of d_out:
    // nothing reads logits until the final GEMM fully overwrites it.
    char* sc = (char*)d_out;
    half8v* hfA = (half8v*)sc;               // layer0 even-step H
    half8v* hfB = (half8v*)(sc + 65536);     // layer0 odd-step H
    half8v* hfC = (half8v*)(sc + 131072);    // layer1 even-step H
    half8v* hfD = (half8v*)(sc + 196608);    // layer1 odd-step H
    int*    flags = (int*)(sc + 262144);     // [256] step counters (both layers)

    // weight conversions (every call; required since inputs are restored each run)
    cvt_f32_f16<<<2048, 256, 0, stream>>>((const float4*)W_ih, (half4v*)Wi_h,
                                          2 * 1024 * 1024 / 4);
    cvt_f32_f16<<<8192, 256, 0, stream>>>((const float4*)W_out, (half4v*)Wout_h,
                                          VOCAB * 1024 / 4);
    cvt_f32_f16<<<2048, 256, 0, stream>>>((const float4*)W_hh, (half4v*)Wh_h,
                                          2 * 1024 * 1024 / 4);
    gather_x<<<MROWS, 256, 0, stream>>>(ix, (const float4*)emb, (half4v*)x_h);
    hf_init<<<32, 256, 0, stream>>>(hid0, hfA, hfC, flags);

    dim3 g1(HID / 128, MROWS / 128);      // (8, 32)
    // layer 0
    gemm_f16_bt<<<g1, 256, 0, stream>>>(x_h, Wi_h, b_ih, xw, MROWS, HID, HID);
    rnn_layer_mfma<<<RNN_WGS, 256, 0, stream>>>(xw, Wh_h, b_hh, hfA, hfB,
                                                y_h, hidT, flags);
    // layer 1
    gemm_f16_bt<<<g1, 256, 0, stream>>>(y_h, Wi_h + 1024 * 1024, b_ih + 1024, xw,
                                        MROWS, HID, HID);
    rnn_layer_mfma<<<RNN_WGS, 256, 0, stream>>>(xw, Wh_h + 1024 * 1024, b_hh + 1024,
                                                hfC, hfD, x_h, hidT + 32 * 1024,
                                                flags + T_SEQ);
    // output projection + bias
    dim3 g3(VOCAB / 128, MROWS / 128);    // (250, 32)
    gemm_f16_bt<<<g3, 256, 0, stream>>>(x_h, Wout_h, b_out, logits, MROWS, VOCAB, HID);
    // in-place log-softmax
    logsoftmax_rows<<<MROWS, 256, 0, stream>>>(logits);
}

// Round 2
// 2922.235 us; speedup vs baseline: 1.8115x; 1.1155x over previous
//
#include <hip/hip_runtime.h>
#include <cstdint>
#include <cstddef>

#define GLOBAL_AS __attribute__((address_space(1)))
#define LDS_AS    __attribute__((address_space(3)))

typedef _Float16 half4v __attribute__((ext_vector_type(4)));
typedef _Float16 half8v __attribute__((ext_vector_type(8)));
typedef float    f32x4  __attribute__((ext_vector_type(4)));
typedef uint32_t u32x4  __attribute__((ext_vector_type(4)));

#define T_SEQ 128
#define NBATCH 32
#define HID   1024
#define VOCAB 32000
#define MROWS (T_SEQ * NBATCH)   // 4096
#define RNN_WGS 16               // weight-resident recurrence workgroups

// ---------------------------------------------------------------- utilities

__device__ __forceinline__ void load16_to_lds(const _Float16* gp, _Float16* lp) {
    // async global->LDS, 16B per lane; LDS dest must be wave-uniform base + lane*16
    __builtin_amdgcn_global_load_lds((const GLOBAL_AS uint32_t*)gp,
                                     (LDS_AS uint32_t*)lp, 16, 0, 0);
}

__device__ __forceinline__ float fast_tanh(float x) {
    // (e^2x - 1)/(e^2x + 1); clamp keeps e2 finite so inf*0 NaN can't happen
    float cx = fminf(fmaxf(x, -9.0f), 9.0f);
    float e2 = __expf(2.0f * cx);
    return (e2 - 1.0f) * __builtin_amdgcn_rcpf(e2 + 1.0f);
}

// ------------------------------------------------------------- conversions

// flat f32 -> f16, 4 elems/thread, grid-stride
__global__ __launch_bounds__(256) void cvt_f32_f16(const float4* __restrict__ src,
                                                   half4v* __restrict__ dst, int n4) {
    int i = blockIdx.x * 256 + threadIdx.x;
    int stride = gridDim.x * 256;
    for (; i < n4; i += stride) {
        float4 v = src[i];
        half4v h = {(_Float16)v.x, (_Float16)v.y, (_Float16)v.z, (_Float16)v.w};
        dst[i] = h;
    }
}

// x_h[r][:] = (f16) emb[ix[r]][:]   r = t*NBATCH+b
__global__ __launch_bounds__(256) void gather_x(const int* __restrict__ ix,
                                                const float4* __restrict__ emb4,
                                                half4v* __restrict__ x4) {
    int r = blockIdx.x;
    int t = threadIdx.x;
    int tok = ix[r];
    float4 v = emb4[(size_t)tok * 256 + t];
    half4v h = {(_Float16)v.x, (_Float16)v.y, (_Float16)v.z, (_Float16)v.w};
    x4[(size_t)r * 256 + t] = h;
}

// Build initial H fragment buffers (A-frag order) for both layers + zero flags.
// Frag layout: element (kt, mt, lane, e) = H[b = mt*16 + (lane&15)]
//                                          [k = kt*32 + (lane>>4)*8 + e]
// stored at half8v index (kt*2 + mt)*64 + lane.
__global__ __launch_bounds__(256) void hf_init(const float* __restrict__ hidden, // [2][32][1024]
                                               half8v* __restrict__ hf_l0,
                                               half8v* __restrict__ hf_l1,
                                               int* __restrict__ flags) {        // [256]
    int idx = blockIdx.x * 256 + threadIdx.x;   // 0..8191
    int l   = idx >> 12;
    int r   = idx & 4095;
    int kt   = r >> 7;
    int mt   = (r >> 6) & 1;
    int lane = r & 63;
    int b  = mt * 16 + (lane & 15);
    int k0 = kt * 32 + (lane >> 4) * 8;
    const float* s = hidden + ((size_t)l << 15) + ((size_t)b << 10) + k0;
    half8v h;
#pragma unroll
    for (int e = 0; e < 8; ++e) h[e] = (_Float16)s[e];
    (l ? hf_l1 : hf_l0)[r] = h;
    if (idx < 256) flags[idx] = 0;
}

// ------------------------------------------------------------- f16 MFMA GEMM
// C[M,N] = A[M,K] * B[N,K]^T + bias[N]    (m97 structure: 128x128 tile, BK=32,
// 256 thr = 4 waves each 64x64, global_load_lds 16B staging)
__global__ __launch_bounds__(256) void gemm_f16_bt(const _Float16* __restrict__ A,
                                                   const _Float16* __restrict__ B,
                                                   const float* __restrict__ bias,
                                                   float* __restrict__ C,
                                                   int M, int N, int K) {
    __shared__ __align__(16) _Float16 As[128 * 32];
    __shared__ __align__(16) _Float16 Bs[128 * 32];
    const int t    = threadIdx.x;
    const int lane = t & 63;
    const int wave = t >> 6;
    const int wm   = (wave >> 1) << 6;
    const int wn   = (wave & 1) << 6;
    const int lr   = lane & 15;
    const int quad = lane >> 4;
    const long mBase = (long)blockIdx.y << 7;
    const long nBase = (long)blockIdx.x << 7;

    const int srow = t >> 2;            // 4 threads/row, 16B each (32 f16 per row)
    const int scol = (t & 3) << 3;
    const _Float16* gA0 = A + (mBase + srow) * (long)K + scol;
    const _Float16* gA1 = A + (mBase + srow + 64) * (long)K + scol;
    const _Float16* gB0 = B + (nBase + srow) * (long)K + scol;
    const _Float16* gB1 = B + (nBase + srow + 64) * (long)K + scol;
    _Float16* lA0 = As + t * 8;
    _Float16* lA1 = As + (t + 256) * 8;
    _Float16* lB0 = Bs + t * 8;
    _Float16* lB1 = Bs + (t + 256) * 8;

    f32x4 acc[4][4] = {};

    for (int k0 = 0; k0 < K; k0 += 32) {
        load16_to_lds(gA0 + k0, lA0);
        load16_to_lds(gA1 + k0, lA1);
        load16_to_lds(gB0 + k0, lB0);
        load16_to_lds(gB1 + k0, lB1);
        __syncthreads();   // drains vmcnt before LDS reads

        half8v aF[4], bF[4];
#pragma unroll
        for (int i = 0; i < 4; ++i) {
            aF[i] = *(const half8v*)&As[(wm + i * 16 + lr) * 32 + quad * 8];
            bF[i] = *(const half8v*)&Bs[(wn + i * 16 + lr) * 32 + quad * 8];
        }
#pragma unroll
        for (int mi = 0; mi < 4; ++mi)
#pragma unroll
            for (int ni = 0; ni < 4; ++ni)
                acc[mi][ni] = __builtin_amdgcn_mfma_f32_16x16x32_f16(
                    aF[mi], bF[ni], acc[mi][ni], 0, 0, 0);
        __syncthreads();
    }

    // C/D layout: col = lane&15, row = quad*4 + r   (m89-verified)
#pragma unroll
    for (int ni = 0; ni < 4; ++ni) {
        long col = nBase + wn + ni * 16 + lr;
        float bv = bias ? bias[col] : 0.0f;
#pragma unroll
        for (int mi = 0; mi < 4; ++mi) {
            long row0 = mBase + wm + mi * 16 + quad * 4;
#pragma unroll
            for (int r = 0; r < 4; ++r)
                C[(row0 + r) * (long)N + col] = acc[mi][ni][r] + bv;
        }
    }
}

// ------------------------------------------------------------- RNN recurrence
// Weight-resident MFMA recurrence, round 2:
//   - Wh slice pinned in VGPRs via asm volatile loads (compiler cannot sink
//     them into the time loop; round-1 VGPR_Count=112 proved it had).
//   - NO __threadfence / atomics. All cross-WG traffic (H frags, epoch flags)
//     uses global_load/store with sc0 sc1 (L1-bypass, write-through to the
//     coherence point, no local allocate) -> no cache maintenance, xw stays
//     L2-cached, H round-trips the LLC only.
//   - Barrier = 64 per-wave monotonic epoch flags. Wave stores flag[g*4+w]=t+1
//     after its own s_waitcnt vmcnt(0) (its H stores are at coherence point);
//     every lane polls flag[lane]; __all(fv >= t+1) exits. No RMW serialization.
//   - y store + next-step xw prefetch issued after the flag store so their
//     latency hides under the poll.
__global__ __launch_bounds__(256, 1) void rnn_layer_mfma(
    const float* __restrict__ xw,        // [4096][1024]  x@Wi^T + b_ih (f32)
    const _Float16* __restrict__ wh,     // [1024][1024]  this layer's Wh (f16)
    const float* __restrict__ bh,        // [1024]
    half8v* __restrict__ hf0,            // frag-ordered H buffer (even steps)
    half8v* __restrict__ hf1,            // frag-ordered H buffer (odd steps)
    _Float16* __restrict__ y,            // [4096][1024]  layer output (f16)
    float* __restrict__ hT,              // [32][1024]    final hidden (f32)
    int* __restrict__ flags)             // [64] per-wave epoch flags, zeroed
{
    const int g    = blockIdx.x;         // j-slice
    const int tid  = threadIdx.x;
    const int w    = tid >> 6;           // wave: K-slice [256w, 256w+256)
    const int lane = tid & 63;
    const int lr   = lane & 15;
    const int quad = lane >> 4;
    const int jbase = g << 6;

    __shared__ float red[4][32][72];     // per-wave partials; 72 keeps float4 16B-aligned

    // ---- preload B fragments, pinned via asm volatile (exactly-once loads) ----
    // bF[nt][kk] = Wh[jbase + nt*16 + lr][(8w+kk)*32 + quad*8 .. +8]
    u32x4 bF[4][8];
#pragma unroll
    for (int nt = 0; nt < 4; ++nt)
#pragma unroll
        for (int kk = 0; kk < 8; ++kk) {
            const void* p = &wh[(size_t)(jbase + nt * 16 + lr) * HID
                                + ((8 * w + kk) * 32 + quad * 8)];
            asm volatile("global_load_dwordx4 %0, %1, off"
                         : "=v"(bF[nt][kk]) : "v"(p));
        }
    asm volatile("s_waitcnt vmcnt(0)" ::: "memory");
    __builtin_amdgcn_sched_barrier(0);

    // ---- reducer-role constants: this thread owns (b=rm, j=jbase+rn..+8) ----
    const int rm = tid >> 3;             // batch row 0..31
    const int rn = (tid & 7) << 3;       // local col 0..56
    float bhv[8];
#pragma unroll
    for (int e = 0; e < 8; ++e) bhv[e] = bh[jbase + rn + e];
    // frag-order H writeback slot for this thread's 8 values
    const int houtIdx = ((2 * g + (rn >> 5)) * 2 + (rm >> 4)) * 64
                        + ((rn >> 3) & 3) * 16 + (rm & 15);

    // prologue xw for t=0
    float xv[8];
    {
        const float* xr = xw + ((size_t)rm << 10) + jbase + rn;
#pragma unroll
        for (int e = 0; e < 8; ++e) xv[e] = xr[e];
    }

    const u32x4* hin = (const u32x4*)hf0;
    u32x4*       hout = (u32x4*)hf1;

    for (int t = 0; t < T_SEQ; ++t) {
        // A fragments: coherent 16B loads straight from the coherence point
        u32x4 aF[2][8];
#pragma unroll
        for (int kk = 0; kk < 8; ++kk)
#pragma unroll
            for (int mt = 0; mt < 2; ++mt) {
                const void* p = hin + ((8 * w + kk) * 2 + mt) * 64 + lane;
                asm volatile("global_load_dwordx4 %0, %1, off sc0 sc1"
                             : "=v"(aF[mt][kk]) : "v"(p));
            }
        asm volatile("s_waitcnt vmcnt(0)" ::: "memory");
        __builtin_amdgcn_sched_barrier(0);

        f32x4 acc[2][4] = {};
#pragma unroll
        for (int kk = 0; kk < 8; ++kk)
#pragma unroll
            for (int mt = 0; mt < 2; ++mt)
#pragma unroll
                for (int nt = 0; nt < 4; ++nt)
                    acc[mt][nt] = __builtin_amdgcn_mfma_f32_16x16x32_f16(
                        __builtin_bit_cast(half8v, aF[mt][kk]),
                        __builtin_bit_cast(half8v, bF[nt][kk]),
                        acc[mt][nt], 0, 0, 0);

        // partials -> LDS   (C/D layout: col=lane&15, row=quad*4+r)
#pragma unroll
        for (int mt = 0; mt < 2; ++mt)
#pragma unroll
            for (int nt = 0; nt < 4; ++nt)
#pragma unroll
                for (int r = 0; r < 4; ++r)
                    red[w][mt * 16 + quad * 4 + r][nt * 16 + lr] = acc[mt][nt][r];
        __syncthreads();

        // cross-wave reduce (float4) + xw + bias + tanh
        float4 lo = *(const float4*)&red[0][rm][rn];
        float4 hi = *(const float4*)&red[0][rm][rn + 4];
#pragma unroll
        for (int ww = 1; ww < 4; ++ww) {
            float4 a = *(const float4*)&red[ww][rm][rn];
            float4 b = *(const float4*)&red[ww][rm][rn + 4];
            lo.x += a.x; lo.y += a.y; lo.z += a.z; lo.w += a.w;
            hi.x += b.x; hi.y += b.y; hi.z += b.z; hi.w += b.w;
        }
        float v[8] = {lo.x, lo.y, lo.z, lo.w, hi.x, hi.y, hi.z, hi.w};
#pragma unroll
        for (int e = 0; e < 8; ++e) v[e] = fast_tanh(v[e] + xv[e] + bhv[e]);
        half8v hv;
#pragma unroll
        for (int e = 0; e < 8; ++e) hv[e] = (_Float16)v[e];

        // H writeback: write-through to coherence point, then drain this wave
        {
            u32x4 hq = __builtin_bit_cast(u32x4, hv);
            void* p = hout + houtIdx;
            asm volatile("global_store_dwordx4 %0, %1, off sc0 sc1"
                         :: "v"(p), "v"(hq) : "memory");
        }
        asm volatile("s_waitcnt vmcnt(0)" ::: "memory");

        // per-wave epoch flag (monotonic, no reset, no RMW)
        if (lane == 0) {
            int ep = t + 1;
            asm volatile("global_store_dword %0, %1, off sc0 sc1"
                         :: "v"(&flags[g * 4 + w]), "v"(ep) : "memory");
        }

        // work that hides under the poll: y store, hT tail, next xw prefetch
        *(half8v*)&y[((size_t)(t * NBATCH + rm) << 10) + jbase + rn] = hv;

        if (t == T_SEQ - 1) {
#pragma unroll
            for (int e = 0; e < 8; ++e)
                hT[((size_t)rm << 10) + jbase + rn + e] = v[e];
        } else {
            const float* xr = xw + ((size_t)((t + 1) * NBATCH + rm) << 10) + jbase + rn;
            float xn[8];
#pragma unroll
            for (int e = 0; e < 8; ++e) xn[e] = xr[e];

            // poll all 64 wave-epochs (lane <-> flag)
            int fv;
            const int* fp = flags + lane;
            do {
                asm volatile("global_load_dword %0, %1, off sc0 sc1\n\t"
                             "s_waitcnt vmcnt(0)"
                             : "=v"(fv) : "v"(fp) : "memory");
            } while (!__all(fv >= t + 1));

#pragma unroll
            for (int e = 0; e < 8; ++e) xv[e] = xn[e];
        }

        u32x4* tmp = (u32x4*)hin;
        hin  = (const u32x4*)hout;
        hout = tmp;
    }
}

// ------------------------------------------------------------- log_softmax
// In-place per row of [4096][32000]; 3 passes (max / sumexp / subtract),
// passes 2-3 ride L2 (row = 128 KB just touched).
__global__ __launch_bounds__(256) void logsoftmax_rows(float* __restrict__ logits) {
    const long r = blockIdx.x;
    float4* row = (float4*)(logits + r * (long)VOCAB);   // 8000 float4
    __shared__ float red[256];
    const int t = threadIdx.x;

    float m = -3.4e38f;
    for (int i = t; i < 8000; i += 256) {
        float4 v = row[i];
        m = fmaxf(m, fmaxf(fmaxf(v.x, v.y), fmaxf(v.z, v.w)));
    }
    red[t] = m; __syncthreads();
    for (int o = 128; o > 0; o >>= 1) {
        if (t < o) red[t] = fmaxf(red[t], red[t + o]);
        __syncthreads();
    }
    m = red[0]; __syncthreads();

    float s = 0.0f;
    for (int i = t; i < 8000; i += 256) {
        float4 v = row[i];
        s += __expf(v.x - m) + __expf(v.y - m) + __expf(v.z - m) + __expf(v.w - m);
    }
    red[t] = s; __syncthreads();
    for (int o = 128; o > 0; o >>= 1) {
        if (t < o) red[t] += red[t + o];
        __syncthreads();
    }
    const float lse = m + __logf(red[0]);

    for (int i = t; i < 8000; i += 256) {
        float4 v = row[i];
        v.x -= lse; v.y -= lse; v.z -= lse; v.w -= lse;
        row[i] = v;
    }
}

// ------------------------------------------------------------------- launch

extern "C" void kernel_launch(void* const* d_in, const int* in_sizes, int n_in,
                              void* d_out, int out_size, void* d_ws, size_t ws_size,
                              hipStream_t stream) {
    const int*   ix    = (const int*)  d_in[0];
    const float* hid0  = (const float*)d_in[1];   // [2,32,1024]
    const float* emb   = (const float*)d_in[2];   // [32000,1024]
    const float* W_ih  = (const float*)d_in[3];   // [2,1024,1024]
    const float* W_hh  = (const float*)d_in[4];   // [2,1024,1024]
    const float* b_ih  = (const float*)d_in[5];   // [2,1024]
    const float* b_hh  = (const float*)d_in[6];   // [2,1024]
    const float* W_out = (const float*)d_in[7];   // [32000,1024]
    const float* b_out = (const float*)d_in[8];   // [32000]

    float* logits = (float*)d_out;                       // [4096][32000]
    float* hidT   = logits + (size_t)MROWS * VOCAB;      // [2][32][1024]

    char* ws = (char*)d_ws;
    _Float16* Wi_h   = (_Float16*)ws;  ws += (size_t)2 * 1024 * 1024 * sizeof(_Float16);
    _Float16* Wout_h = (_Float16*)ws;  ws += (size_t)VOCAB * 1024 * sizeof(_Float16);
    _Float16* Wh_h   = (_Float16*)ws;  ws += (size_t)2 * 1024 * 1024 * sizeof(_Float16);
    _Float16* x_h    = (_Float16*)ws;  ws += (size_t)MROWS * 1024 * sizeof(_Float16);
    _Float16* y_h    = (_Float16*)ws;  ws += (size_t)MROWS * 1024 * sizeof(_Float16);
    float*    xw     = (float*)ws;     ws += (size_t)MROWS * 1024 * sizeof(float);

    // H fragment ping-pong buffers + epoch flags live in the head of d_out:
    // nothing reads logits until the final GEMM fully overwrites it.
    char* sc = (char*)d_out;
    half8v* hfA = (half8v*)sc;               // layer0 even-step H
    half8v* hfB = (half8v*)(sc + 65536);     // layer0 odd-step H
    half8v* hfC = (half8v*)(sc + 131072);    // layer1 even-step H
    half8v* hfD = (half8v*)(sc + 196608);    // layer1 odd-step H
    int*    flags = (int*)(sc + 262144);     // [2][64] per-wave epoch flags

    // weight conversions (every call; required since inputs are restored each run)
    cvt_f32_f16<<<2048, 256, 0, stream>>>((const float4*)W_ih, (half4v*)Wi_h,
                                          2 * 1024 * 1024 / 4);
    cvt_f32_f16<<<8192, 256, 0, stream>>>((const float4*)W_out, (half4v*)Wout_h,
                                          VOCAB * 1024 / 4);
    cvt_f32_f16<<<2048, 256, 0, stream>>>((const float4*)W_hh, (half4v*)Wh_h,
                                          2 * 1024 * 1024 / 4);
    gather_x<<<MROWS, 256, 0, stream>>>(ix, (const float4*)emb, (half4v*)x_h);
    hf_init<<<32, 256, 0, stream>>>(hid0, hfA, hfC, flags);

    dim3 g1(HID / 128, MROWS / 128);      // (8, 32)
    // layer 0
    gemm_f16_bt<<<g1, 256, 0, stream>>>(x_h, Wi_h, b_ih, xw, MROWS, HID, HID);
    rnn_layer_mfma<<<RNN_WGS, 256, 0, stream>>>(xw, Wh_h, b_hh, hfA, hfB,
                                                y_h, hidT, flags);
    // layer 1
    gemm_f16_bt<<<g1, 256, 0, stream>>>(y_h, Wi_h + 1024 * 1024, b_ih + 1024, xw,
                                        MROWS, HID, HID);
    rnn_layer_mfma<<<RNN_WGS, 256, 0, stream>>>(xw, Wh_h + 1024 * 1024, b_hh + 1024,
                                                hfC, hfD, x_h, hidT + 32 * 1024,
                                                flags + 64);
    // output projection + bias
    dim3 g3(VOCAB / 128, MROWS / 128);    // (250, 32)
    gemm_f16_bt<<<g3, 256, 0, stream>>>(x_h, Wout_h, b_out, logits, MROWS, VOCAB, HID);
    // in-place log-softmax
    logsoftmax_rows<<<MROWS, 256, 0, stream>>>(logits);
}